// Round 1
// baseline (102.962 us; speedup 1.0000x reference)
//
#include <hip/hip_runtime.h>

// SpatialTransformer bilinear sampler, B=1, C=32, H=W=512.
// out[0,c,h,w] = bilinear_sample(I[c], y = (H-1-h)+dy_t+1, x = w+dx_t+1) on the
// zero-padded (H+2,W+2) image — implemented as flip-on-store: each thread
// handles source pixel (h,w), writes to row H-1-h.

constexpr int H = 512;
constexpr int W = 512;
constexpr int C = 32;

__global__ __launch_bounds__(256) void st_bilinear_kernel(
    const float* __restrict__ I,      // (C,H,W)
    const float* __restrict__ dxt,    // (H,W)
    const float* __restrict__ dyt,    // (H,W)
    float* __restrict__ out)          // (C,H,W), flipped along H
{
    const int pix = blockIdx.x * blockDim.x + threadIdx.x;
    if (pix >= H * W) return;
    const int h = pix >> 9;        // /W
    const int w = pix & (W - 1);   // %W

    // Padded-image coordinates (pad=1): x in [0, W+1], y in [0, H+1]
    const float x = dxt[pix] + (float)w + 1.0f;
    const float y = dyt[pix] + (float)h + 1.0f;

    const int fx = (int)floorf(x);
    const int fy = (int)floorf(y);
    const int maxx = W + 1;        // Wp - 1 = 513
    const int maxy = H + 1;

    const int x0 = min(max(fx,     0), maxx);
    const int x1 = min(max(fx + 1, 0), maxx);
    const int y0 = min(max(fy,     0), maxy);
    const int y1 = min(max(fy + 1, 0), maxy);

    const float ddx = (float)x1 - x;   // after clipping, exactly as reference
    const float ddy = (float)y1 - y;

    float wa = ddx * ddy;                   // tap (y0, x0)
    float wb = ddx * (1.0f - ddy);          // tap (y1, x0)  [idx_b uses x1,y0 — see below]
    float wc = (1.0f - ddx) * ddy;
    float wd = (1.0f - ddx) * (1.0f - ddy);
    // Reference mapping: Ia=(y0,x0) wa, Ib=(y0,x1) wb, Ic=(y1,x0) wc, Id=(y1,x1) wd.

    // Translate padded coords -> unpadded I coords; zero-pad == weight-zeroing.
    const bool vx0 = (x0 >= 1) & (x0 <= W);
    const bool vx1 = (x1 >= 1) & (x1 <= W);
    const bool vy0 = (y0 >= 1) & (y0 <= H);
    const bool vy1 = (y1 >= 1) & (y1 <= H);

    int offA = (y0 - 1) * W + (x0 - 1);
    int offB = (y0 - 1) * W + (x1 - 1);
    int offC = (y1 - 1) * W + (x0 - 1);
    int offD = (y1 - 1) * W + (x1 - 1);

    if (!(vy0 & vx0)) { wa = 0.0f; offA = 0; }
    if (!(vy0 & vx1)) { wb = 0.0f; offB = 0; }
    if (!(vy1 & vx0)) { wc = 0.0f; offC = 0; }
    if (!(vy1 & vx1)) { wd = 0.0f; offD = 0; }

    const int outPix = (H - 1 - h) * W + w;   // flip along H on store

    #pragma unroll 8
    for (int c = 0; c < C; ++c) {
        const float* __restrict__ Ic = I + c * (H * W);
        const float v = wa * Ic[offA] + wb * Ic[offB] + wc * Ic[offC] + wd * Ic[offD];
        out[c * (H * W) + outPix] = v;
    }
}

extern "C" void kernel_launch(void* const* d_in, const int* in_sizes, int n_in,
                              void* d_out, int out_size, void* d_ws, size_t ws_size,
                              hipStream_t stream) {
    const float* I   = (const float*)d_in[0];
    const float* dxt = (const float*)d_in[1];
    const float* dyt = (const float*)d_in[2];
    float* out = (float*)d_out;

    const int npix = H * W;
    const int block = 256;
    const int grid = (npix + block - 1) / block;
    st_bilinear_kernel<<<grid, block, 0, stream>>>(I, dxt, dyt, out);
}